// Round 3
// baseline (1132.894 us; speedup 1.0000x reference)
//
#include <hip/hip_runtime.h>
#include <math.h>

// Problem constants (fixed by setup_inputs)
#define BQ 2048
#define DD 1024
#define CC 65536
#define KSEL 8
#define NSTRIPE 32
#define SC (CC / NSTRIPE)   // 2048 cols per stripe
#define GTM 128
#define GTN 128
#define GBK 32
#define NTILES (SC / GTN)   // 16 col-tiles per stripe
#define LCAND 8             // per-stripe top-L (union property needs 8)
#define TRES 32             // candidates rescored in fp64 per row

typedef unsigned int u32;
typedef unsigned short ushort_t;
typedef __attribute__((ext_vector_type(8))) short bf16x8;
typedef __attribute__((ext_vector_type(4))) float f32x4;

// ---------------- workspace layout (bytes), total 6,832,128 ----------------
// 0        : double qinv[BQ]                (16384)
// 16384    : double kinv[CC]                (524288)
// 540672   : ushort qn[BQ*DD]               (4194304)   dead after gemm; aliased:
//   540672 :   float counts[CC]             (262144)
//   802816 :   int   sel_idx[BQ*32]         (262144)
//   1064960:   double sel_val[BQ*32]        (524288)
//   1589248:   int   topk[BQ*8]             (65536)
// 4734976  : uint  cand[BQ*NSTRIPE*LCAND]   (2097152)
// kn (bf16, 128 MB) lives in d_out[0 .. 134217728) — overwritten by gather at end.

#define FENCE() asm volatile("" ::: "memory")
#define LGKM0() asm volatile("s_waitcnt lgkmcnt(0)" ::: "memory")

__device__ __forceinline__ ushort_t f2bf(float f) {
    u32 u = __builtin_bit_cast(u32, f);
    return (ushort_t)((u + 0x7FFFu + ((u >> 16) & 1u)) >> 16);
}

__device__ __forceinline__ void gl_lds16(const ushort_t* g, ushort_t* l) {
    __builtin_amdgcn_global_load_lds(
        (const __attribute__((address_space(1))) u32*)g,
        (__attribute__((address_space(3))) u32*)l, 16, 0, 0);
}

// Fused: fp64 inverse L2 norm + normalize + bf16 convert, one pass over inputs.
// One block (256 threads) per row; keys rows [0,CC), then q rows.
__global__ __launch_bounds__(256) void normconv_kernel(
    const float* __restrict__ q, const float* __restrict__ keys,
    double* __restrict__ qinv, double* __restrict__ kinv,
    ushort_t* __restrict__ qn, ushort_t* __restrict__ kn)
{
    __shared__ double red[4];
    const int row = blockIdx.x;
    const int t = threadIdx.x;
    const bool iskey = row < CC;
    const float* src = iskey ? keys + (size_t)row * DD
                             : q + (size_t)(row - CC) * DD;
    float4 v = ((const float4*)src)[t];
    double s = (double)v.x * v.x + (double)v.y * v.y +
               (double)v.z * v.z + (double)v.w * v.w;
    for (int off = 32; off > 0; off >>= 1) s += __shfl_down(s, off);
    if ((t & 63) == 0) red[t >> 6] = s;
    __syncthreads();
    const double tot = red[0] + red[1] + red[2] + red[3];
    const double inv = 1.0 / fmax(sqrt(tot), 1e-12);
    if (t == 0) {
        if (iskey) kinv[row] = inv; else qinv[row - CC] = inv;
    }
    const float invf = (float)inv;
    ushort4 o;
    o.x = f2bf(v.x * invf); o.y = f2bf(v.y * invf);
    o.z = f2bf(v.z * invf); o.w = f2bf(v.w * invf);
    ushort_t* dst = iskey ? kn + (size_t)row * DD
                          : qn + (size_t)(row - CC) * DD;
    ((ushort4*)dst)[t] = o;
}

// MFMA bf16 GEMM fused with exact per-stripe top-8 per row.
// v3: LDS cut to 49,664 B (tilebuf -> 32-col chunks) => 3 blocks/CU.
// Keeps: dbuf + 1-deep cross-tile prefetch (counted vmcnt(4), raw barriers),
// both-sides k-segment XOR swizzle, setprio around MFMA, 2-thread-per-row
// scan, bijective XCD block swizzle.
// grid = (BQ/128, NSTRIPE), block = 256 (4 waves, 2x2 wave grid).
__global__ __launch_bounds__(256, 3) void gemm_topk_kernel(
    const ushort_t* __restrict__ qn, const ushort_t* __restrict__ kn,
    unsigned* __restrict__ cand)
{
    __shared__ ushort_t As[2][GTM * GBK];  // 8 KB x2
    __shared__ ushort_t Bs[2][GTN * GBK];  // 8 KB x2
    __shared__ float tilebuf[GTM][33];     // 32-col chunk, +1 pad  16.9 KB
    // total LDS = 49,664 B -> 3 blocks/CU (148,992 <= 163,840)

    const int tid = threadIdx.x;
    const int wid = tid >> 6;
    const int lane = tid & 63;
    const int wy = wid >> 1, wx = wid & 1;
    const int l15 = lane & 15, quad = lane >> 4;

    // bijective XCD swizzle: 512 blocks, 8 XCDs, 64 consecutive ids per XCD.
    const int flat = blockIdx.y * 16 + blockIdx.x;   // gridDim.x == 16
    const int swz  = (flat & 7) * 64 + (flat >> 3);
    const int bx = swz & 15, by = swz >> 4;
    const int m0 = bx * GTM;
    const int sbase = by * SC;

    // staging: 512 16B segments per tile; thread handles e and e+256.
    // k-segment XOR swizzle x(row) = (row>>1)&3 applied to the GLOBAL source
    // (linear LDS dest required by global_load_lds) and to the ds_read addr.
    const int e0 = tid, e1 = tid + 256;
    const int ks0 = (((e0 & 3) ^ ((e0 >> 3) & 3)) * 8);
    const int ks1 = (((e1 & 3) ^ ((e1 >> 3) & 3)) * 8);
    const ushort_t* gA0 = qn + (size_t)(m0 + (e0 >> 2)) * DD + ks0;
    const ushort_t* gA1 = qn + (size_t)(m0 + (e1 >> 2)) * DD + ks1;
    const ushort_t* gB0 = kn + (size_t)(sbase + (e0 >> 2)) * DD + ks0;
    const ushort_t* gB1 = kn + (size_t)(sbase + (e1 >> 2)) * DD + ks1;

#define STAGE(buf, k0_) do {                         \
        gl_lds16(gA0 + (k0_), As[buf] + e0 * 8);     \
        gl_lds16(gA1 + (k0_), As[buf] + e1 * 8);     \
        gl_lds16(gB0 + (k0_), Bs[buf] + e0 * 8);     \
        gl_lds16(gB1 + (k0_), Bs[buf] + e1 * 8);     \
    } while (0)

    float tv[LCAND];
    int ti[LCAND];
#pragma unroll
    for (int l = 0; l < LCAND; ++l) { tv[l] = -3.0e38f; ti[l] = 0; }
    float minv = -3.0e38f;
    int minpos = 0;

    const int swz15 = (l15 >> 1) & 3;    // read-side XOR bits

    STAGE(0, 0);                         // prologue: 4 loads in flight

    for (int nt = 0; nt < NTILES; ++nt) {
        const int cbase = sbase + nt * GTN;

        f32x4 acc[4][4];
#pragma unroll
        for (int i = 0; i < 4; ++i)
#pragma unroll
            for (int j = 0; j < 4; ++j) acc[i][j] = (f32x4)0.0f;

#pragma unroll 2
        for (int kt = 0; kt < DD / GBK; ++kt) {
            const int cur = kt & 1;
            if (kt < DD / GBK - 1) {
                STAGE(cur ^ 1, (kt + 1) * GBK);          // prefetch next k-step
                asm volatile("s_waitcnt vmcnt(4)" ::: "memory");
            } else if (nt < NTILES - 1) {
                gB0 += (size_t)GTN * DD;                 // advance to next col-tile
                gB1 += (size_t)GTN * DD;
                STAGE(cur ^ 1, 0);                       // cross-tile prefetch
                asm volatile("s_waitcnt vmcnt(4)" ::: "memory");
            } else {
                asm volatile("s_waitcnt vmcnt(0)" ::: "memory");
            }
            __builtin_amdgcn_s_barrier();                // buf[cur] ready for all waves
            FENCE();
            __builtin_amdgcn_s_setprio(1);

            bf16x8 af[4], bfr[4];
#pragma unroll
            for (int ri = 0; ri < 4; ++ri)
                af[ri] = *(const bf16x8*)(As[cur] +
                    (wy * 64 + ri * 16 + l15) * GBK + ((quad ^ swz15) * 8));
#pragma unroll
            for (int ci = 0; ci < 4; ++ci)
                bfr[ci] = *(const bf16x8*)(Bs[cur] +
                    (wx * 64 + ci * 16 + l15) * GBK + ((quad ^ swz15) * 8));
#pragma unroll
            for (int ri = 0; ri < 4; ++ri)
#pragma unroll
                for (int ci = 0; ci < 4; ++ci)
                    acc[ri][ci] = __builtin_amdgcn_mfma_f32_16x16x32_bf16(
                        af[ri], bfr[ci], acc[ri][ci], 0, 0, 0);

            __builtin_amdgcn_s_setprio(0);
            FENCE();
            __builtin_amdgcn_s_barrier();                // readers done; next STAGE may overwrite
            FENCE();
        }

        // epilogue: dump 32-col chunks to LDS, 2-thread-per-row running top-8.
        // Raw barriers with lgkmcnt drain only — keeps prefetch loads in flight.
        for (int c4 = 0; c4 < 4; ++c4) {
            LGKM0();
            __builtin_amdgcn_s_barrier();                // prior scan readers done
            FENCE();
            if (wx == (c4 >> 1)) {
                const int cilo = (c4 & 1) * 2;
#pragma unroll
                for (int ri = 0; ri < 4; ++ri)
#pragma unroll
                    for (int cx = 0; cx < 2; ++cx)
#pragma unroll
                        for (int r = 0; r < 4; ++r)
                            tilebuf[wy * 64 + ri * 16 + quad * 4 + r][cx * 16 + l15] =
                                acc[ri][cilo + cx][r];
            }
            LGKM0();
            __builtin_amdgcn_s_barrier();                // dump visible
            FENCE();
            {
                const int rr = tid & 127;                // row
                const int jb = (tid >> 7) << 4;          // owner: cols 0-15, helper: 16-31
                const int gc0 = cbase + c4 * 32 + jb;
                for (int j = 0; j < 16; ++j) {
                    float v = tilebuf[rr][jb + j];
                    if (v > minv) {
                        tv[minpos] = v; ti[minpos] = gc0 + j;
                        minv = tv[0]; minpos = 0;
#pragma unroll
                        for (int l = 1; l < LCAND; ++l)
                            if (tv[l] < minv) { minv = tv[l]; minpos = l; }
                    }
                }
            }
        }
    }

    // stripe end: helper publishes its top-8, owner merges and writes cand.
    LGKM0();
    __builtin_amdgcn_s_barrier();                        // last scans done
    FENCE();
    if (tid >= 128) {
        const int r2 = tid - 128;
#pragma unroll
        for (int l = 0; l < LCAND; ++l) {
            tilebuf[r2][l] = tv[l];
            tilebuf[r2][16 + l] = __int_as_float(ti[l]);
        }
    }
    LGKM0();
    __builtin_amdgcn_s_barrier();
    FENCE();
    if (tid < GTM) {
#pragma unroll
        for (int c = 0; c < LCAND; ++c) {
            float v = tilebuf[tid][c];
            int idx = __float_as_int(tilebuf[tid][16 + c]);
            if (v > minv) {
                tv[minpos] = v; ti[minpos] = idx;
                minv = tv[0]; minpos = 0;
#pragma unroll
                for (int l = 1; l < LCAND; ++l)
                    if (tv[l] < minv) { minv = tv[l]; minpos = l; }
            }
        }
        unsigned* dst = cand + (size_t)(m0 + tid) * (NSTRIPE * LCAND) + by * LCAND;
#pragma unroll
        for (int l = 0; l < LCAND; ++l)
            dst[l] = ((unsigned)f2bf(tv[l]) << 16) | (unsigned)(ti[l] & 0xFFFF);
    }
#undef STAGE
}

// One wave per row: top-32 of 256 packed candidates (signed-int compare works:
// all real candidate sims > 0 -> packed positive; padding is negative).
// Also zeroes counts[] (runs after gemm, counts aliases dead qn space).
__global__ __launch_bounds__(256) void merge_kernel(
    const int* __restrict__ cand, int* __restrict__ sel_idx,
    float* __restrict__ counts)
{
    const int gid = blockIdx.x * 256 + threadIdx.x;
    if (gid < CC) counts[gid] = 0.0f;
    const int row = gid >> 6;
    const int lane = threadIdx.x & 63;
    const int* cv = cand + (size_t)row * (NSTRIPE * LCAND);
    int v[4];
#pragma unroll
    for (int u = 0; u < 4; ++u) v[u] = cv[lane + 64 * u];
    for (int r = 0; r < TRES; ++r) {
        int bv = v[0];
#pragma unroll
        for (int u = 1; u < 4; ++u) bv = max(bv, v[u]);
#pragma unroll
        for (int off = 1; off < 64; off <<= 1) bv = max(bv, __shfl_xor(bv, off));
#pragma unroll
        for (int u = 0; u < 4; ++u)
            if (v[u] == bv) v[u] = (int)0x80000000;   // packed values unique per row
        if (lane == 0) sel_idx[row * TRES + r] = bv & 0xFFFF;
    }
}

// One block per row: exact fp64 cosine sim on ORIGINAL fp32 data.
// q row cached in LDS (read once); each wave handles 8 of the 32 candidates.
// Per-candidate accumulation order identical to previous version (bit-exact).
__global__ __launch_bounds__(256) void rescore_kernel(
    const float* __restrict__ q, const float* __restrict__ keys,
    const double* __restrict__ qinv, const double* __restrict__ kinv,
    const int* __restrict__ sel_idx, double* __restrict__ sel_val)
{
    __shared__ float qs[DD];               // 4 KB
    const int b = blockIdx.x;
    const int t = threadIdx.x;
    ((float4*)qs)[t] = ((const float4*)(q + (size_t)b * DD))[t];
    __syncthreads();
    const int wv = t >> 6, lane = t & 63;
    const double qi = qinv[b];
    for (int cc = wv; cc < TRES; cc += 4) {
        const int c = sel_idx[b * TRES + cc];
        const float4* kr = (const float4*)(keys + (size_t)c * DD);
        double s = 0.0;
#pragma unroll
        for (int u = 0; u < 4; ++u) {
            float4 a = ((const float4*)qs)[lane + 64 * u];
            float4 k4 = kr[lane + 64 * u];
            s += (double)a.x * k4.x + (double)a.y * k4.y +
                 (double)a.z * k4.z + (double)a.w * k4.w;
        }
        for (int off = 32; off > 0; off >>= 1) s += __shfl_down(s, off);
        if (lane == 0) sel_val[b * TRES + cc] = s * qi * kinv[c];
    }
}

// One thread per row: insertion-sort 32 fp64 candidates desc (tie -> lower idx).
__global__ __launch_bounds__(256) void finalize_kernel(
    const double* __restrict__ sel_val, const int* __restrict__ sel_idx,
    int* __restrict__ topk_idx, float* __restrict__ counts)
{
    const int b = blockIdx.x * 256 + threadIdx.x;
    if (b >= BQ) return;
    double bv[KSEL]; int bi[KSEL];
#pragma unroll
    for (int j = 0; j < KSEL; ++j) { bv[j] = -1.0e300; bi[j] = 0x7fffffff; }
    for (int t = 0; t < TRES; ++t) {
        double v = sel_val[b * TRES + t];
        int idx = sel_idx[b * TRES + t];
        int p = KSEL;
        while (p > 0 && (v > bv[p - 1] || (v == bv[p - 1] && idx < bi[p - 1]))) --p;
        if (p < KSEL) {
            for (int s = KSEL - 1; s > p; --s) { bv[s] = bv[s - 1]; bi[s] = bi[s - 1]; }
            bv[p] = v; bi[p] = idx;
        }
    }
    for (int j = 0; j < KSEL; ++j) {
        topk_idx[b * KSEL + j] = bi[j];
        atomicAdd(&counts[bi[j]], 1.0f);
    }
}

// One block per (b, j): bit-exact row copies from ORIGINAL keys/values.
// Overwrites the kn scratch living in d_out — must run after gemm (it does).
__global__ __launch_bounds__(256) void gather_kernel(
    const float* __restrict__ keys, const float* __restrict__ values,
    const int* __restrict__ topk_idx, float* __restrict__ out_k,
    float* __restrict__ out_v)
{
    const int pair = blockIdx.x;               // b*8 + j
    const int c = topk_idx[pair];
    const int t = threadIdx.x;
    const float4* ks = (const float4*)(keys + (size_t)c * DD);
    const float4* vs = (const float4*)(values + (size_t)c * DD);
    float4* ok = (float4*)out_k + (size_t)pair * (DD / 4);
    float4* ov = (float4*)out_v + (size_t)pair * (DD / 4);
    ok[t] = ks[t];
    ov[t] = vs[t];
}

__global__ __launch_bounds__(256) void usage_kernel(
    const float* __restrict__ usage_in, const float* __restrict__ counts,
    float* __restrict__ out_u)
{
    const int c = blockIdx.x * 256 + threadIdx.x;
    out_u[c] = usage_in[c] + counts[c];
}

extern "C" void kernel_launch(void* const* d_in, const int* in_sizes, int n_in,
                              void* d_out, int out_size, void* d_ws, size_t ws_size,
                              hipStream_t stream)
{
    const float* q      = (const float*)d_in[0];
    const float* keys   = (const float*)d_in[1];
    const float* values = (const float*)d_in[2];
    const float* usage  = (const float*)d_in[3];
    // d_in[4] is k == 8, hardcoded.

    char* ws = (char*)d_ws;
    double* qinv     = (double*)(ws + 0);
    double* kinv     = (double*)(ws + 16384);
    ushort_t* qn     = (ushort_t*)(ws + 540672);
    // aliases into dead-after-gemm qn space:
    float* counts    = (float*)(ws + 540672);
    int* sel_idx     = (int*)(ws + 802816);
    double* sel_val  = (double*)(ws + 1064960);
    int* topk        = (int*)(ws + 1589248);
    unsigned* cand   = (unsigned*)(ws + 4734976);

    float* out_k = (float*)d_out;
    float* out_v = out_k + (size_t)BQ * KSEL * DD;
    float* out_u = out_v + (size_t)BQ * KSEL * DD;
    ushort_t* kn = (ushort_t*)d_out;   // 128 MB scratch, dies before gather

    normconv_kernel<<<CC + BQ, 256, 0, stream>>>(q, keys, qinv, kinv, qn, kn);

    dim3 g2(BQ / GTM, NSTRIPE);
    gemm_topk_kernel<<<g2, 256, 0, stream>>>(qn, kn, cand);

    merge_kernel<<<BQ / 4, 256, 0, stream>>>((const int*)cand, sel_idx, counts);

    rescore_kernel<<<BQ, 256, 0, stream>>>(q, keys, qinv, kinv, sel_idx, sel_val);

    finalize_kernel<<<BQ / 256, 256, 0, stream>>>(sel_val, sel_idx, topk, counts);

    gather_kernel<<<BQ * KSEL, 256, 0, stream>>>(keys, values, topk, out_k, out_v);

    usage_kernel<<<CC / 256, 256, 0, stream>>>(usage, counts, out_u);
}

// Round 4
// 1045.200 us; speedup vs baseline: 1.0839x; 1.0839x over previous
//
#include <hip/hip_runtime.h>
#include <math.h>

// Problem constants (fixed by setup_inputs)
#define BQ 2048
#define DD 1024
#define CC 65536
#define KSEL 8
#define NSTRIPE 32
#define SC (CC / NSTRIPE)   // 2048 cols per stripe
#define BM2 256             // block tile M
#define BN2 256             // block tile N
#define GBK 32
#define NTILES2 (SC / BN2)  // 8 col-tiles per stripe
#define LCAND 8             // per-stripe top-L (union property needs 8)
#define TRES 32             // candidates rescored in fp64 per row

typedef unsigned int u32;
typedef unsigned short ushort_t;
typedef __attribute__((ext_vector_type(8))) short bf16x8;
typedef __attribute__((ext_vector_type(4))) float f32x4;

// ---------------- workspace layout (bytes), total 6,832,128 ----------------
// 0        : double qinv[BQ]                (16384)
// 16384    : double kinv[CC]                (524288)
// 540672   : ushort qn[BQ*DD]               (4194304)   dead after gemm; aliased:
//   540672 :   float counts[CC]             (262144)
//   802816 :   int   sel_idx[BQ*32]         (262144)
//   1064960:   double sel_val[BQ*32]        (524288)
//   1589248:   int   topk[BQ*8]             (65536)
// 4734976  : uint  cand[BQ*NSTRIPE*LCAND]   (2097152)
// kn (bf16, 128 MB) lives in d_out[0 .. 134217728) — overwritten by gather at end.

#define FENCE() asm volatile("" ::: "memory")
#define LGKM0() asm volatile("s_waitcnt lgkmcnt(0)" ::: "memory")

__device__ __forceinline__ ushort_t f2bf(float f) {
    u32 u = __builtin_bit_cast(u32, f);
    return (ushort_t)((u + 0x7FFFu + ((u >> 16) & 1u)) >> 16);
}

__device__ __forceinline__ void gl_lds16(const ushort_t* g, ushort_t* l) {
    __builtin_amdgcn_global_load_lds(
        (const __attribute__((address_space(1))) u32*)g,
        (__attribute__((address_space(3))) u32*)l, 16, 0, 0);
}

// Fused: fp64 inverse L2 norm + normalize + bf16 convert, one pass over inputs.
// One block (256 threads) per row; keys rows [0,CC), then q rows.
__global__ __launch_bounds__(256) void normconv_kernel(
    const float* __restrict__ q, const float* __restrict__ keys,
    double* __restrict__ qinv, double* __restrict__ kinv,
    ushort_t* __restrict__ qn, ushort_t* __restrict__ kn)
{
    __shared__ double red[4];
    const int row = blockIdx.x;
    const int t = threadIdx.x;
    const bool iskey = row < CC;
    const float* src = iskey ? keys + (size_t)row * DD
                             : q + (size_t)(row - CC) * DD;
    float4 v = ((const float4*)src)[t];
    double s = (double)v.x * v.x + (double)v.y * v.y +
               (double)v.z * v.z + (double)v.w * v.w;
    for (int off = 32; off > 0; off >>= 1) s += __shfl_down(s, off);
    if ((t & 63) == 0) red[t >> 6] = s;
    __syncthreads();
    const double tot = red[0] + red[1] + red[2] + red[3];
    const double inv = 1.0 / fmax(sqrt(tot), 1e-12);
    if (t == 0) {
        if (iskey) kinv[row] = inv; else qinv[row - CC] = inv;
    }
    const float invf = (float)inv;
    ushort4 o;
    o.x = f2bf(v.x * invf); o.y = f2bf(v.y * invf);
    o.z = f2bf(v.z * invf); o.w = f2bf(v.w * invf);
    ushort_t* dst = iskey ? kn + (size_t)row * DD
                          : qn + (size_t)(row - CC) * DD;
    ((ushort4*)dst)[t] = o;
}

// MFMA bf16 GEMM fused with exact per-stripe top-8 per row.
// v4: 256x256 block tile, 512 threads (8 waves, 2x4 grid), 128x64 per wave.
// Rationale: kernel is LDS-read-BW-bound (12 KB ds_read feeds 16 MFMAs at
// 64x64/wave -> MfmaUtil pinned ~20%). 128x64/wave feeds 32 MFMAs from the
// same 12 KB -> LDS-read ~= MFMA-issue (balanced). Staging traffic halves.
// Keeps: dbuf + 1-deep cross-tile prefetch (counted vmcnt(4), raw barriers),
// both-sides k-segment XOR swizzle, setprio, owner/helper scan (identical
// col partition to v3 -> bit-identical results), bijective XCD swizzle.
// grid = (BQ/256, NSTRIPE) = (8, 32) = 256 blocks = 1 block/CU.
__global__ __launch_bounds__(512, 2) void gemm_topk_kernel(
    const ushort_t* __restrict__ qn, const ushort_t* __restrict__ kn,
    unsigned* __restrict__ cand)
{
    __shared__ ushort_t As[2][BM2 * GBK];  // 16 KB x2
    __shared__ ushort_t Bs[2][BN2 * GBK];  // 16 KB x2
    __shared__ float tilebuf[BM2][33];     // 32-col chunk, +1 pad  33,792 B
    // total LDS = 99,328 B (1 block/CU; grid-limited anyway)

    const int t = threadIdx.x;             // 0..511
    const int wid = t >> 6;
    const int lane = t & 63;
    const int wy = wid >> 2, wx = wid & 3; // 2x4 wave grid
    const int l15 = lane & 15, quad = lane >> 4;

    // bijective XCD swizzle: 256 blocks, 8 XCDs, 32 consecutive ids per XCD.
    const int flat = blockIdx.y * 8 + blockIdx.x;    // gridDim.x == 8
    const int swz  = (flat & 7) * 32 + (flat >> 3);
    const int bx = swz & 7, by = swz >> 3;
    const int m0 = bx * BM2;
    const int sbase = by * SC;

    // staging: 2048 16B segments per (A+B) K-step tile pair; thread t handles
    // A segs {t, t+512} and B segs {t, t+512}.
    // k-segment XOR swizzle x(row) = (row>>1)&3 applied to the GLOBAL source
    // (linear LDS dest required by global_load_lds) and to the ds_read addr.
    // Note (row>>1)&3 is identical for row and row+128 -> same ks for both.
    const int ks = (((t & 3) ^ ((t >> 3) & 3)) * 8);
    const ushort_t* gA0 = qn + (size_t)(m0 + (t >> 2)) * DD + ks;
    const ushort_t* gA1 = gA0 + (size_t)128 * DD;
    const ushort_t* gB0 = kn + (size_t)(sbase + (t >> 2)) * DD + ks;
    const ushort_t* gB1 = gB0 + (size_t)128 * DD;

#define STAGE(buf, k0_) do {                              \
        gl_lds16(gA0 + (k0_), As[buf] + t * 8);           \
        gl_lds16(gA1 + (k0_), As[buf] + (t + 512) * 8);   \
        gl_lds16(gB0 + (k0_), Bs[buf] + t * 8);           \
        gl_lds16(gB1 + (k0_), Bs[buf] + (t + 512) * 8);   \
    } while (0)

    float tv[LCAND];
    int ti[LCAND];
#pragma unroll
    for (int l = 0; l < LCAND; ++l) { tv[l] = -3.0e38f; ti[l] = 0; }
    float minv = -3.0e38f;
    int minpos = 0;

    const int swz15 = (l15 >> 1) & 3;    // read-side XOR bits

    STAGE(0, 0);                         // prologue: 4 loads in flight

    for (int nt = 0; nt < NTILES2; ++nt) {
        const int cbase = sbase + nt * BN2;

        f32x4 acc[8][4];
#pragma unroll
        for (int i = 0; i < 8; ++i)
#pragma unroll
            for (int j = 0; j < 4; ++j) acc[i][j] = (f32x4)0.0f;

#pragma unroll 2
        for (int kt = 0; kt < DD / GBK; ++kt) {
            const int cur = kt & 1;
            if (kt < DD / GBK - 1) {
                STAGE(cur ^ 1, (kt + 1) * GBK);          // prefetch next k-step
                asm volatile("s_waitcnt vmcnt(4)" ::: "memory");
            } else if (nt < NTILES2 - 1) {
                gB0 += (size_t)BN2 * DD;                 // advance to next col-tile
                gB1 += (size_t)BN2 * DD;
                STAGE(cur ^ 1, 0);                       // cross-tile prefetch
                asm volatile("s_waitcnt vmcnt(4)" ::: "memory");
            } else {
                asm volatile("s_waitcnt vmcnt(0)" ::: "memory");
            }
            __builtin_amdgcn_s_barrier();                // buf[cur] ready for all waves
            FENCE();
            __builtin_amdgcn_s_setprio(1);

            bf16x8 af[8], bfr[4];
#pragma unroll
            for (int ri = 0; ri < 8; ++ri)
                af[ri] = *(const bf16x8*)(As[cur] +
                    (wy * 128 + ri * 16 + l15) * GBK + ((quad ^ swz15) * 8));
#pragma unroll
            for (int ci = 0; ci < 4; ++ci)
                bfr[ci] = *(const bf16x8*)(Bs[cur] +
                    (wx * 64 + ci * 16 + l15) * GBK + ((quad ^ swz15) * 8));
#pragma unroll
            for (int ri = 0; ri < 8; ++ri)
#pragma unroll
                for (int ci = 0; ci < 4; ++ci)
                    acc[ri][ci] = __builtin_amdgcn_mfma_f32_16x16x32_bf16(
                        af[ri], bfr[ci], acc[ri][ci], 0, 0, 0);

            __builtin_amdgcn_s_setprio(0);
            FENCE();
            __builtin_amdgcn_s_barrier();                // readers done; next STAGE may overwrite
            FENCE();
        }

        // epilogue: dump 32-col chunks to LDS, 2-thread-per-row running top-8.
        // Col partition per row (owner: cols 0-15 mod 32, helper: 16-31 mod 32,
        // ascending) is IDENTICAL to v3 -> bit-identical candidate selection.
        // Raw barriers with lgkmcnt drain only — keeps prefetch loads in flight.
#pragma unroll
        for (int c8 = 0; c8 < 8; ++c8) {
            LGKM0();
            __builtin_amdgcn_s_barrier();                // prior scan readers done
            FENCE();
            if (wx == (c8 >> 1)) {
                const int cilo = (c8 & 1) * 2;
#pragma unroll
                for (int ri = 0; ri < 8; ++ri)
#pragma unroll
                    for (int cx = 0; cx < 2; ++cx)
#pragma unroll
                        for (int r = 0; r < 4; ++r)
                            tilebuf[wy * 128 + ri * 16 + quad * 4 + r][cx * 16 + l15] =
                                acc[ri][cilo + cx][r];
            }
            LGKM0();
            __builtin_amdgcn_s_barrier();                // dump visible
            FENCE();
            {
                const int rr = t & 255;                  // row
                const int jb = (t >> 8) << 4;            // owner: cols 0-15, helper: 16-31
                const int gc0 = cbase + c8 * 32 + jb;
                for (int j = 0; j < 16; ++j) {
                    float v = tilebuf[rr][jb + j];
                    if (v > minv) {
                        tv[minpos] = v; ti[minpos] = gc0 + j;
                        minv = tv[0]; minpos = 0;
#pragma unroll
                        for (int l = 1; l < LCAND; ++l)
                            if (tv[l] < minv) { minv = tv[l]; minpos = l; }
                    }
                }
            }
        }
    }

    // stripe end: helper publishes its top-8, owner merges and writes cand.
    LGKM0();
    __builtin_amdgcn_s_barrier();                        // last scans done
    FENCE();
    if (t >= 256) {
        const int r2 = t - 256;
#pragma unroll
        for (int l = 0; l < LCAND; ++l) {
            tilebuf[r2][l] = tv[l];
            tilebuf[r2][16 + l] = __int_as_float(ti[l]);
        }
    }
    LGKM0();
    __builtin_amdgcn_s_barrier();
    FENCE();
    if (t < 256) {
#pragma unroll
        for (int c = 0; c < LCAND; ++c) {
            float v = tilebuf[t][c];
            int idx = __float_as_int(tilebuf[t][16 + c]);
            if (v > minv) {
                tv[minpos] = v; ti[minpos] = idx;
                minv = tv[0]; minpos = 0;
#pragma unroll
                for (int l = 1; l < LCAND; ++l)
                    if (tv[l] < minv) { minv = tv[l]; minpos = l; }
            }
        }
        unsigned* dst = cand + (size_t)(m0 + t) * (NSTRIPE * LCAND) + by * LCAND;
#pragma unroll
        for (int l = 0; l < LCAND; ++l)
            dst[l] = ((unsigned)f2bf(tv[l]) << 16) | (unsigned)(ti[l] & 0xFFFF);
    }
#undef STAGE
}

// One wave per row: top-32 of 256 packed candidates (signed-int compare works:
// all real candidate sims > 0 -> packed positive; padding is negative).
// Also zeroes counts[] (runs after gemm, counts aliases dead qn space).
__global__ __launch_bounds__(256) void merge_kernel(
    const int* __restrict__ cand, int* __restrict__ sel_idx,
    float* __restrict__ counts)
{
    const int gid = blockIdx.x * 256 + threadIdx.x;
    if (gid < CC) counts[gid] = 0.0f;
    const int row = gid >> 6;
    const int lane = threadIdx.x & 63;
    const int* cv = cand + (size_t)row * (NSTRIPE * LCAND);
    int v[4];
#pragma unroll
    for (int u = 0; u < 4; ++u) v[u] = cv[lane + 64 * u];
    for (int r = 0; r < TRES; ++r) {
        int bv = v[0];
#pragma unroll
        for (int u = 1; u < 4; ++u) bv = max(bv, v[u]);
#pragma unroll
        for (int off = 1; off < 64; off <<= 1) bv = max(bv, __shfl_xor(bv, off));
#pragma unroll
        for (int u = 0; u < 4; ++u)
            if (v[u] == bv) v[u] = (int)0x80000000;   // packed values unique per row
        if (lane == 0) sel_idx[row * TRES + r] = bv & 0xFFFF;
    }
}

// One block per row: exact fp64 cosine sim on ORIGINAL fp32 data.
// q row cached in LDS (read once); each wave handles 8 of the 32 candidates.
// Per-candidate accumulation order identical to previous version (bit-exact).
__global__ __launch_bounds__(256) void rescore_kernel(
    const float* __restrict__ q, const float* __restrict__ keys,
    const double* __restrict__ qinv, const double* __restrict__ kinv,
    const int* __restrict__ sel_idx, double* __restrict__ sel_val)
{
    __shared__ float qs[DD];               // 4 KB
    const int b = blockIdx.x;
    const int t = threadIdx.x;
    ((float4*)qs)[t] = ((const float4*)(q + (size_t)b * DD))[t];
    __syncthreads();
    const int wv = t >> 6, lane = t & 63;
    const double qi = qinv[b];
    for (int cc = wv; cc < TRES; cc += 4) {
        const int c = sel_idx[b * TRES + cc];
        const float4* kr = (const float4*)(keys + (size_t)c * DD);
        double s = 0.0;
#pragma unroll
        for (int u = 0; u < 4; ++u) {
            float4 a = ((const float4*)qs)[lane + 64 * u];
            float4 k4 = kr[lane + 64 * u];
            s += (double)a.x * k4.x + (double)a.y * k4.y +
                 (double)a.z * k4.z + (double)a.w * k4.w;
        }
        for (int off = 32; off > 0; off >>= 1) s += __shfl_down(s, off);
        if (lane == 0) sel_val[b * TRES + cc] = s * qi * kinv[c];
    }
}

// One thread per row: insertion-sort 32 fp64 candidates desc (tie -> lower idx).
__global__ __launch_bounds__(256) void finalize_kernel(
    const double* __restrict__ sel_val, const int* __restrict__ sel_idx,
    int* __restrict__ topk_idx, float* __restrict__ counts)
{
    const int b = blockIdx.x * 256 + threadIdx.x;
    if (b >= BQ) return;
    double bv[KSEL]; int bi[KSEL];
#pragma unroll
    for (int j = 0; j < KSEL; ++j) { bv[j] = -1.0e300; bi[j] = 0x7fffffff; }
    for (int t = 0; t < TRES; ++t) {
        double v = sel_val[b * TRES + t];
        int idx = sel_idx[b * TRES + t];
        int p = KSEL;
        while (p > 0 && (v > bv[p - 1] || (v == bv[p - 1] && idx < bi[p - 1]))) --p;
        if (p < KSEL) {
            for (int s = KSEL - 1; s > p; --s) { bv[s] = bv[s - 1]; bi[s] = bi[s - 1]; }
            bv[p] = v; bi[p] = idx;
        }
    }
    for (int j = 0; j < KSEL; ++j) {
        topk_idx[b * KSEL + j] = bi[j];
        atomicAdd(&counts[bi[j]], 1.0f);
    }
}

// One block per (b, j): bit-exact row copies from ORIGINAL keys/values.
// Overwrites the kn scratch living in d_out — must run after gemm (it does).
__global__ __launch_bounds__(256) void gather_kernel(
    const float* __restrict__ keys, const float* __restrict__ values,
    const int* __restrict__ topk_idx, float* __restrict__ out_k,
    float* __restrict__ out_v)
{
    const int pair = blockIdx.x;               // b*8 + j
    const int c = topk_idx[pair];
    const int t = threadIdx.x;
    const float4* ks = (const float4*)(keys + (size_t)c * DD);
    const float4* vs = (const float4*)(values + (size_t)c * DD);
    float4* ok = (float4*)out_k + (size_t)pair * (DD / 4);
    float4* ov = (float4*)out_v + (size_t)pair * (DD / 4);
    ok[t] = ks[t];
    ov[t] = vs[t];
}

__global__ __launch_bounds__(256) void usage_kernel(
    const float* __restrict__ usage_in, const float* __restrict__ counts,
    float* __restrict__ out_u)
{
    const int c = blockIdx.x * 256 + threadIdx.x;
    out_u[c] = usage_in[c] + counts[c];
}

extern "C" void kernel_launch(void* const* d_in, const int* in_sizes, int n_in,
                              void* d_out, int out_size, void* d_ws, size_t ws_size,
                              hipStream_t stream)
{
    const float* q      = (const float*)d_in[0];
    const float* keys   = (const float*)d_in[1];
    const float* values = (const float*)d_in[2];
    const float* usage  = (const float*)d_in[3];
    // d_in[4] is k == 8, hardcoded.

    char* ws = (char*)d_ws;
    double* qinv     = (double*)(ws + 0);
    double* kinv     = (double*)(ws + 16384);
    ushort_t* qn     = (ushort_t*)(ws + 540672);
    // aliases into dead-after-gemm qn space:
    float* counts    = (float*)(ws + 540672);
    int* sel_idx     = (int*)(ws + 802816);
    double* sel_val  = (double*)(ws + 1064960);
    int* topk        = (int*)(ws + 1589248);
    unsigned* cand   = (unsigned*)(ws + 4734976);

    float* out_k = (float*)d_out;
    float* out_v = out_k + (size_t)BQ * KSEL * DD;
    float* out_u = out_v + (size_t)BQ * KSEL * DD;
    ushort_t* kn = (ushort_t*)d_out;   // 128 MB scratch, dies before gather

    normconv_kernel<<<CC + BQ, 256, 0, stream>>>(q, keys, qinv, kinv, qn, kn);

    dim3 g2(BQ / BM2, NSTRIPE);
    gemm_topk_kernel<<<g2, 512, 0, stream>>>(qn, kn, cand);

    merge_kernel<<<BQ / 4, 256, 0, stream>>>((const int*)cand, sel_idx, counts);

    rescore_kernel<<<BQ, 256, 0, stream>>>(q, keys, qinv, kinv, sel_idx, sel_val);

    finalize_kernel<<<BQ / 256, 256, 0, stream>>>(sel_val, sel_idx, topk, counts);

    gather_kernel<<<BQ * KSEL, 256, 0, stream>>>(keys, values, topk, out_k, out_v);

    usage_kernel<<<CC / 256, 256, 0, stream>>>(usage, counts, out_u);
}